// Round 3
// baseline (711.633 us; speedup 1.0000x reference)
//
#include <hip/hip_runtime.h>

// Problem constants (fixed by the reference).
#define BB 8
#define CI 8
#define CO 8
#define DD 32
#define HH 128
#define WW 128
#define HW (HH * WW)

// One thread: 8 consecutive w positions x 4 c_out = 32 fp32 accumulators.
// (R2 post-mortem: 64 accumulators spilled even under a 128-VGPR cap, and
// exec-masked spill/reload around the divergent row guard corrupted results
// on dirty scratch. 32 accs ≈ 60 VGPRs -> provably no spill.)
// Block: 256 threads = 16 w-tiles (full W=128) x 16 h rows.
// Grid: 2 co-halves * B * D * (H/16) = 4096 blocks; co-half is the LOW
// blockIdx bit so consecutive blocks share the same x tile (L2 locality).
__global__ __launch_bounds__(256, 6) void conv3d_act_kernel(
    const float* __restrict__ x,
    const float* __restrict__ wgt,
    const float* __restrict__ bias,
    float* __restrict__ out)
{
    const int tid = threadIdx.x;
    const int wt  = tid & 15;   // w-tile index, 0..15
    const int hl  = tid >> 4;   // local h row, 0..15

    int bx = blockIdx.x;
    const int coh = bx & 1;         // c_out half: 0 -> co 0..3, 1 -> co 4..7
    bx >>= 1;
    const int hb = bx & 7;          // H/16 = 8
    bx >>= 3;
    const int d  = bx & 31;         // D = 32
    const int b  = bx >> 5;         // B = 8

    const int h   = hb * 16 + hl;
    const int w0  = wt * 8;
    const int co0 = coh * 4;

    float acc[32];
    #pragma unroll
    for (int i = 0; i < 32; ++i) acc[i] = 0.f;

    const float* xb = x + (size_t)b * CI * DD * HW;

    for (int ci = 0; ci < CI; ++ci) {
        const float* xc = xb + ci * DD * HW;
        #pragma unroll
        for (int kd = 0; kd < 3; ++kd) {
            const int dd = d + kd - 1;
            if ((unsigned)dd >= DD) continue;           // block-uniform branch
            const float* xd = xc + dd * HW;
            #pragma unroll
            for (int kh = 0; kh < 3; ++kh) {
                const int hh = h + kh - 1;
                const bool vrow = (unsigned)hh < HH;    // divergent only at block h-edges
                const float* row = xd + hh * WW + w0;

                float4 A  = make_float4(0.f, 0.f, 0.f, 0.f);
                float4 Bv = make_float4(0.f, 0.f, 0.f, 0.f);
                float  xl = 0.f, xr = 0.f;
                if (vrow) {
                    A  = *(const float4*)(row);         // w0 .. w0+3 (16B aligned)
                    Bv = *(const float4*)(row + 4);     // w0+4 .. w0+7
                    if (wt > 0)  xl = row[-1];          // left halo (zero-pad at w=0)
                    if (wt < 15) xr = row[8];           // right halo (zero-pad at w=127)
                }
                const float xv[10] = {xl, A.x, A.y, A.z, A.w, Bv.x, Bv.y, Bv.z, Bv.w, xr};

                // 3*4*8 = 96 FMAs; weight operand is wave-uniform -> v_fmac(v, s, v)
                #pragma unroll
                for (int kw = 0; kw < 3; ++kw) {
                    #pragma unroll
                    for (int co = 0; co < 4; ++co) {
                        const float wv = wgt[(((co0 + co) * CI + ci) * 3 + kd) * 9 + kh * 3 + kw];
                        #pragma unroll
                        for (int w = 0; w < 8; ++w)
                            acc[co * 8 + w] = fmaf(xv[w + kw], wv, acc[co * 8 + w]);
                    }
                }
            }
        }
    }

    // Epilogue: relu -> (leaky_relu == identity after relu) -> tanh-GELU -> sigmoid -> +bias[c]
    const size_t obase = (size_t)b * CO * DD * HW + (size_t)(co0) * DD * HW
                       + (size_t)d * HW + (size_t)h * WW + w0;
    #pragma unroll
    for (int co = 0; co < 4; ++co) {
        const float bco = bias[co0 + co];
        float r[8];
        #pragma unroll
        for (int w = 0; w < 8; ++w) {
            float y = fmaxf(acc[co * 8 + w], 0.f);
            // t = sqrt(2/pi) * (y + 0.044715 y^3); gelu = y * (1 - 1/(1+e^{2t}))
            float t = 0.7978845608028654f * (y + 0.044715f * y * y * y);
            float e = __builtin_amdgcn_exp2f(2.8853900817779268f * t);   // e^{2t}
            float g = y - y * __builtin_amdgcn_rcpf(1.f + e);
            // sigmoid(g) = 1 / (1 + e^{-g})
            float s = __builtin_amdgcn_rcpf(1.f + __builtin_amdgcn_exp2f(-1.4426950408889634f * g));
            r[w] = s + bco;
        }
        float* orow = out + obase + (size_t)co * DD * HW;
        *(float4*)(orow)     = make_float4(r[0], r[1], r[2], r[3]);
        *(float4*)(orow + 4) = make_float4(r[4], r[5], r[6], r[7]);
    }
}

extern "C" void kernel_launch(void* const* d_in, const int* in_sizes, int n_in,
                              void* d_out, int out_size, void* d_ws, size_t ws_size,
                              hipStream_t stream) {
    const float* x    = (const float*)d_in[0];
    const float* wgt  = (const float*)d_in[1];
    const float* bias = (const float*)d_in[2];
    float* out = (float*)d_out;

    dim3 grid(2 * BB * DD * (HH / 16));   // 4096 blocks
    dim3 block(256);
    conv3d_act_kernel<<<grid, block, 0, stream>>>(x, wgt, bias, out);
}

// Round 4
// 404.617 us; speedup vs baseline: 1.7588x; 1.7588x over previous
//
#include <hip/hip_runtime.h>

// Problem constants (fixed by the reference).
#define BB 8
#define CI 8
#define CO 8
#define DD 32
#define HH 128
#define WW 128
#define HW (HH * WW)

// One thread: 4 consecutive w positions x all 8 c_out = 32 fp32 accumulators.
//
// Register-pressure post-mortem (R1..R3):
//   R1: 64 accs, default bounds -> VGPR=64, AGPR-shuffle overhead, 244 us.
//   R3: 32 accs, __launch_bounds__(256,6) -> allocator pathology: VGPR=40,
//       680 MB of HBM scratch-spill writes, 584 us.
// Fix: DEFAULT launch bounds (compiler targets 64 VGPRs) and a live set that
// genuinely fits: 32 accs + 6-float window + addresses ~= 50 VGPRs. The
// 6-float window feeds 3kw*8co*4w = 96 FMAs (16 FMA per loaded float, same
// reuse ratio as R1's 64-acc tile) so FMA issue still dominates VALU.
//
// Block: 256 threads = 32 w-tiles (full W=128) x 8 h rows.
// Grid: B * D * (H/8) = 8*32*16 = 4096 blocks.
__global__ void conv3d_act_kernel(
    const float* __restrict__ x,
    const float* __restrict__ wgt,
    const float* __restrict__ bias,
    float* __restrict__ out)
{
    const int tid = threadIdx.x;
    const int wt  = tid & 31;   // w-tile index, 0..31
    const int hl  = tid >> 5;   // local h row, 0..7

    int bx = blockIdx.x;
    const int hb = bx & 15;         // H/8 = 16
    bx >>= 4;
    const int d  = bx & 31;         // D = 32
    const int b  = bx >> 5;         // B = 8

    const int h  = hb * 8 + hl;
    const int w0 = wt * 4;

    float acc[32];
    #pragma unroll
    for (int i = 0; i < 32; ++i) acc[i] = 0.f;

    const float* xb = x + (size_t)b * CI * DD * HW;

    for (int ci = 0; ci < CI; ++ci) {
        const float* xc = xb + ci * DD * HW;
        #pragma unroll
        for (int kd = 0; kd < 3; ++kd) {
            const int dd = d + kd - 1;
            if ((unsigned)dd >= DD) continue;           // block-uniform branch
            const float* xd = xc + dd * HW;
            #pragma unroll
            for (int kh = 0; kh < 3; ++kh) {
                const int hh = h + kh - 1;
                const bool vrow = (unsigned)hh < HH;    // divergent only at global h edges
                const float* row = xd + hh * WW + w0;

                float4 A = make_float4(0.f, 0.f, 0.f, 0.f);
                float xl = 0.f, xr = 0.f;
                if (vrow) {
                    A = *(const float4*)(row);          // w0..w0+3 (16B aligned)
                    if (wt > 0)  xl = row[-1];          // left halo (zero-pad at w=0)
                    if (wt < 31) xr = row[4];           // right halo (zero-pad at w=127)
                }
                const float xv[6] = {xl, A.x, A.y, A.z, A.w, xr};

                // 3*8*4 = 96 FMAs; weight operand is wave-uniform -> v_fmac(v, s, v)
                #pragma unroll
                for (int kw = 0; kw < 3; ++kw) {
                    #pragma unroll
                    for (int co = 0; co < 8; ++co) {
                        const float wv = wgt[((co * CI + ci) * 3 + kd) * 9 + kh * 3 + kw];
                        #pragma unroll
                        for (int w = 0; w < 4; ++w)
                            acc[co * 4 + w] = fmaf(xv[w + kw], wv, acc[co * 4 + w]);
                    }
                }
            }
        }
    }

    // Epilogue: relu -> (leaky_relu == identity after relu) -> tanh-GELU -> sigmoid -> +bias[c]
    const size_t obase = (size_t)b * CO * DD * HW + (size_t)d * HW + (size_t)h * WW + w0;
    #pragma unroll
    for (int co = 0; co < 8; ++co) {
        const float bco = bias[co];
        float r[4];
        #pragma unroll
        for (int w = 0; w < 4; ++w) {
            float y = fmaxf(acc[co * 4 + w], 0.f);
            // t = sqrt(2/pi) * (y + 0.044715 y^3); gelu = y * (1 - 1/(1+e^{2t}))
            float t = 0.7978845608028654f * (y + 0.044715f * y * y * y);
            float e = __builtin_amdgcn_exp2f(2.8853900817779268f * t);   // e^{2t}
            float g = y - y * __builtin_amdgcn_rcpf(1.f + e);
            // sigmoid(g) = 1 / (1 + e^{-g})
            float s = __builtin_amdgcn_rcpf(1.f + __builtin_amdgcn_exp2f(-1.4426950408889634f * g));
            r[w] = s + bco;
        }
        float* orow = out + obase + (size_t)co * DD * HW;
        *(float4*)(orow) = make_float4(r[0], r[1], r[2], r[3]);
    }
}

extern "C" void kernel_launch(void* const* d_in, const int* in_sizes, int n_in,
                              void* d_out, int out_size, void* d_ws, size_t ws_size,
                              hipStream_t stream) {
    const float* x    = (const float*)d_in[0];
    const float* wgt  = (const float*)d_in[1];
    const float* bias = (const float*)d_in[2];
    float* out = (float*)d_out;

    dim3 grid(BB * DD * (HH / 8));   // 4096 blocks
    dim3 block(256);
    conv3d_act_kernel<<<grid, block, 0, stream>>>(x, wgt, bias, out);
}

// Round 6
// 279.250 us; speedup vs baseline: 2.5484x; 1.4489x over previous
//
#include <hip/hip_runtime.h>

// conv3d(8ci->8co, 3x3x3, same) + relu/leaky/gelu/sigmoid + bias, via bf16 MFMA.
//
// GEMM view: D[m][n] = sum_k A[m][k] * B[k][n]
//   m = w-position (16 per MFMA tile), n = c_out (8 used of 16),
//   k = tap*8 + ci, tap = kd*9+kh*3+kw in [0,27), padded to 28 taps (K=224, 7 steps).
// LDS x-layout is [slice][h][w][ci] bf16 (ci innermost, 16 B per spatial point):
// one lane's A fragment (1 tap x 8 ci) = one ds_read_b128. Weights = B operand,
// preloaded to 28 VGPRs. 4-slot d-slice ring, one barrier per d iteration.
//
// R5 post-mortem: ring-slot off-by-one. Slice dg is staged into slot (dg+1)&3,
// so tap kd (slice d+kd-1) lives in slot (d+kd)&3; R5 read (d+kd+1)&3 -> conv
// over slices d..d+2 (d-shifted) AND kd=2 raced the concurrent stage(d+2)
// write. Fixed: kdo[t] = kd.

#define CIN 8
#define COUT 8
#define DDIM 32
#define HDIM 128
#define WDIM 128
#define HWSZ (HDIM * WDIM)           // 16384
#define CISTR (DDIM * HWSZ)          // x ci stride in floats

#define ROWPTS 66                    // w = -1..64 (64-wide tile + halo)
#define ROWB   (ROWPTS * 16)         // 1056 B
#define SROWS  6                     // h = -1..4 (4-high tile + halo)
#define SLICEPTS (SROWS * ROWPTS)    // 396 points
#define SLICEB (SROWS * ROWB)        // 6336 B
#define NSLOT 4
#define LDSB (NSLOT * SLICEB)        // 25344 B

typedef short short8 __attribute__((ext_vector_type(8)));
typedef float floatx4 __attribute__((ext_vector_type(4)));

static __device__ __forceinline__ unsigned f2bf(float f) {
    unsigned u = __builtin_bit_cast(unsigned, f);
    return (u + 0x7FFFu + ((u >> 16) & 1u)) >> 16;   // RTN-even bf16
}

static __device__ __forceinline__ float act(float v, float bco) {
    float y = fmaxf(v, 0.f);                         // relu (leaky is identity after relu)
    float t = 0.7978845608028654f * (y + 0.044715f * y * y * y);
    float e = __builtin_amdgcn_exp2f(2.8853900817779268f * t);       // e^{2t}
    float g = y - y * __builtin_amdgcn_rcpf(1.f + e);                // tanh-gelu
    float s = __builtin_amdgcn_rcpf(1.f + __builtin_amdgcn_exp2f(-1.4426950408889634f * g));
    return s + bco;                                  // sigmoid + channel bias
}

// Block: 256 threads = 4 waves; wave w handles output h-row (h0+w), 4 w-chunks of 16.
// Grid: 2 wb * 32 hb * 8 b * 2 dsplit = 1024 blocks; 16 d-iterations per block.
__global__ __launch_bounds__(256, 4) void conv3d_mfma_kernel(
    const float* __restrict__ x,
    const float* __restrict__ wgt,
    const float* __restrict__ bias,
    float* __restrict__ out)
{
    __shared__ __align__(16) char lds[LDSB];

    const int tid  = threadIdx.x;
    const int lane = tid & 63;
    const int wid  = tid >> 6;        // wave id = local h row 0..3
    const int m    = lane & 15;       // A-row (w pos) for A; n (c_out) for B and C/D
    const int g    = lane >> 4;       // k-group 0..3

    int bx = blockIdx.x;
    const int wb = bx & 1;   bx >>= 1;
    const int hb = bx & 31;  bx >>= 5;
    const int b  = bx & 7;   bx >>= 3;
    const int d0 = bx * 16;           // d split
    const int h0 = hb * 4;
    const int W0 = wb * 64;

    const float* xb = x + (size_t)b * CIN * CISTR;

    // ---- B fragments (weights), 7 k-steps, lane: n=m(lane&15), k-run tap=4t+g, ci=j ----
    short8 bw[7];
    #pragma unroll
    for (int t = 0; t < 7; ++t) {
        const int tap = 4 * t + g;
        #pragma unroll
        for (int j = 0; j < 8; ++j) {
            float v = (m < 8 && tap < 27) ? wgt[(m * CIN + j) * 27 + tap] : 0.f;
            bw[t][j] = (short)f2bf(v);
        }
    }
    const float bco = (m < 8) ? bias[m] : 0.f;

    // ---- per-lane A-address invariants ----
    // slice (d+kd-1) lives in slot ((d+kd-1)+1)&3 = (d+kd)&3  ->  kdo[t] = kd
    int kdo[7], inv[7];
    #pragma unroll
    for (int t = 0; t < 7; ++t) {
        const int tap = 4 * t + g;    // 0..27 (27 = zero pad; B=0 so value irrelevant)
        const int kd = tap / 9, r = tap % 9;
        const int kh = r / 3, kw = r % 3;
        kdo[t] = kd;
        inv[t] = kh * ROWB + (m + kw) * 16 + wid * ROWB;
    }

    // ---- staging: slice dg -> slot (dg+1)&3, zero-fill outside the volume ----
    auto stage = [&](int dg) {
        char* sb = lds + ((dg + 1) & 3) * SLICEB;
        const float* xs = xb + (size_t)dg * HWSZ;
        #pragma unroll
        for (int p0 = 0; p0 < 512; p0 += 256) {
            const int p = p0 + tid;
            if (p < SLICEPTS) {
                const int hh = p / ROWPTS, ww = p - hh * ROWPTS;
                const int hg = h0 + hh - 1, wg = W0 + ww - 1;
                const bool ok = ((unsigned)dg < DDIM) & ((unsigned)hg < HDIM) & ((unsigned)wg < WDIM);
                const float* src = xs + hg * WDIM + wg;
                unsigned q[4];
                #pragma unroll
                for (int c = 0; c < 4; ++c) {
                    float v0 = ok ? src[(2 * c    ) * CISTR] : 0.f;   // coalesced per-ci loads
                    float v1 = ok ? src[(2 * c + 1) * CISTR] : 0.f;
                    q[c] = f2bf(v0) | (f2bf(v1) << 16);
                }
                *(int4*)(sb + p * 16) = make_int4(q[0], q[1], q[2], q[3]);  // consecutive b128: no conflict
            }
        }
    };

    stage(d0 - 1); stage(d0); stage(d0 + 1);
    __syncthreads();

    for (int d = d0; d < d0 + 16; ++d) {
        stage(d + 2);   // writes slot (d+3)&3; compute reads slots (d..d+2)&3 — disjoint

        floatx4 acc0 = {0,0,0,0}, acc1 = {0,0,0,0}, acc2 = {0,0,0,0}, acc3 = {0,0,0,0};
        #pragma unroll
        for (int t = 0; t < 7; ++t) {
            const char* ap = lds + ((d + kdo[t]) & 3) * SLICEB + inv[t];
            short8 a0 = __builtin_bit_cast(short8, *(const int4*)(ap      ));
            short8 a1 = __builtin_bit_cast(short8, *(const int4*)(ap + 256));
            short8 a2 = __builtin_bit_cast(short8, *(const int4*)(ap + 512));
            short8 a3 = __builtin_bit_cast(short8, *(const int4*)(ap + 768));
            acc0 = __builtin_amdgcn_mfma_f32_16x16x32_bf16(a0, bw[t], acc0, 0, 0, 0);
            acc1 = __builtin_amdgcn_mfma_f32_16x16x32_bf16(a1, bw[t], acc1, 0, 0, 0);
            acc2 = __builtin_amdgcn_mfma_f32_16x16x32_bf16(a2, bw[t], acc2, 0, 0, 0);
            acc3 = __builtin_amdgcn_mfma_f32_16x16x32_bf16(a3, bw[t], acc3, 0, 0, 0);
        }

        // C/D: n = lane&15 (c_out), rows m = g*4+reg -> 4 consecutive w -> float4 store
        if (m < 8) {
            float* op = out + ((size_t)(b * COUT + m) * DDIM + d) * HWSZ
                            + (h0 + wid) * WDIM + W0 + g * 4;
            *(float4*)(op)      = make_float4(act(acc0[0],bco), act(acc0[1],bco), act(acc0[2],bco), act(acc0[3],bco));
            *(float4*)(op + 16) = make_float4(act(acc1[0],bco), act(acc1[1],bco), act(acc1[2],bco), act(acc1[3],bco));
            *(float4*)(op + 32) = make_float4(act(acc2[0],bco), act(acc2[1],bco), act(acc2[2],bco), act(acc2[3],bco));
            *(float4*)(op + 48) = make_float4(act(acc3[0],bco), act(acc3[1],bco), act(acc3[2],bco), act(acc3[3],bco));
        }
        __syncthreads();
    }
}

extern "C" void kernel_launch(void* const* d_in, const int* in_sizes, int n_in,
                              void* d_out, int out_size, void* d_ws, size_t ws_size,
                              hipStream_t stream) {
    const float* x    = (const float*)d_in[0];
    const float* wgt  = (const float*)d_in[1];
    const float* bias = (const float*)d_in[2];
    float* out = (float*)d_out;

    dim3 grid(2 * 32 * 8 * 2);   // wb * hb * b * dsplit = 1024
    dim3 block(256);
    conv3d_mfma_kernel<<<grid, block, 0, stream>>>(x, wgt, bias, out);
}